// Round 4
// baseline (2205.680 us; speedup 1.0000x reference)
//
#include <hip/hip_runtime.h>
#include <hip/hip_bf16.h>

// Sizes fixed by the problem
#define B  2048
#define D  4096
#define D3 12288   // 3*D
#define L  3

struct Ptrs8 { const float* p[8]; };

typedef float          f32x4 __attribute__((ext_vector_type(4)));
typedef unsigned int   u32x4 __attribute__((ext_vector_type(4)));
typedef unsigned short u16x4 __attribute__((ext_vector_type(4)));

__device__ __forceinline__ f32x4 ldnt4(const float* p) {
    return __builtin_nontemporal_load(reinterpret_cast<const f32x4*>(p));
}
__device__ __forceinline__ f32x4 ld4(const float* p) {
    return *reinterpret_cast<const f32x4*>(p);
}

__device__ __forceinline__ unsigned short f2bf(float f) {
    union { float f; unsigned int u; } v; v.f = f;
    unsigned int r = v.u + 0x7FFFu + ((v.u >> 16) & 1u);  // round-nearest-even
    return (unsigned short)(r >> 16);
}
__device__ __forceinline__ float bf_lo(unsigned int u) {
    union { unsigned int u; float f; } v; v.u = u << 16; return v.f;
}
__device__ __forceinline__ float bf_hi(unsigned int u) {
    union { unsigned int u; float f; } v; v.u = u & 0xFFFF0000u; return v.f;
}

// ---------------------------------------------------------------------------
// K1: column means of the 8 [B, D] inputs. 4 independent accumulators for MLP.
// NT loads: inputs streamed once; keep out of LLC.
// ---------------------------------------------------------------------------
__global__ void k_mean_partial(Ptrs8 in, float* __restrict__ partials) {
    const int cc = blockIdx.x, rc = blockIdx.y, m = blockIdx.z;
    const float* __restrict__ src = in.p[m];
    const int col0 = cc * 1024 + threadIdx.x * 4;
    const size_t base = (size_t)(rc * 128) * D + col0;
    f32x4 a0 = {0,0,0,0}, a1 = {0,0,0,0}, a2 = {0,0,0,0}, a3 = {0,0,0,0};
    for (int r = 0; r < 128; r += 4) {
        a0 += ldnt4(src + base + (size_t)(r + 0) * D);
        a1 += ldnt4(src + base + (size_t)(r + 1) * D);
        a2 += ldnt4(src + base + (size_t)(r + 2) * D);
        a3 += ldnt4(src + base + (size_t)(r + 3) * D);
    }
    const f32x4 acc = (a0 + a1) + (a2 + a3);
    *reinterpret_cast<f32x4*>(partials + ((size_t)(m * 16 + rc)) * D + col0) = acc;
}

__global__ void k_mean_finalize(const float* __restrict__ partials,
                                float* __restrict__ means,
                                float* __restrict__ h,
                                float* __restrict__ svec) {
    const int d = blockIdx.x * 256 + threadIdx.x;
    float mv[8];
    #pragma unroll
    for (int m = 0; m < 8; ++m) {
        float s = 0.f;
        #pragma unroll
        for (int rc = 0; rc < 16; ++rc) s += partials[(size_t)(m * 16 + rc) * D + d];
        mv[m] = s * (1.0f / (float)B);
        means[m * D + d] = mv[m];
    }
    float ssum = 0.f;
    #pragma unroll
    for (int j = 0; j < 4; ++j) {          // shared rows = pre means (inputs 4..7)
        h[j * D + d] = mv[4 + j];
        ssum += mv[4 + j];
    }
    #pragma unroll
    for (int s = 0; s < 4; ++s)            // stream rows = now means (inputs 0..3)
        h[(4 + s) * D + d] = mv[s];
    svec[d] = ssum;
}

// ---------------------------------------------------------------------------
// K3: aggmsg[d'] = sum_d svec[d] * W[d][d'].  grid (4,128): 512 blocks,
// 32 rows each, 4 independent accumulators. NT on W (streamed once).
// ---------------------------------------------------------------------------
__global__ void k_aggmsg_partial(const float* __restrict__ Wl,
                                 const float* __restrict__ svec,
                                 float* __restrict__ partials) {
    const int col0 = blockIdx.x * 1024 + threadIdx.x * 4;
    const int row0 = blockIdx.y * 32;
    f32x4 a0 = {0,0,0,0}, a1 = {0,0,0,0}, a2 = {0,0,0,0}, a3 = {0,0,0,0};
    #pragma unroll
    for (int r = 0; r < 32; r += 4) {
        a0 += svec[row0 + r + 0] * ldnt4(Wl + (size_t)(row0 + r + 0) * D + col0);
        a1 += svec[row0 + r + 1] * ldnt4(Wl + (size_t)(row0 + r + 1) * D + col0);
        a2 += svec[row0 + r + 2] * ldnt4(Wl + (size_t)(row0 + r + 2) * D + col0);
        a3 += svec[row0 + r + 3] * ldnt4(Wl + (size_t)(row0 + r + 3) * D + col0);
    }
    const f32x4 acc = (a0 + a1) + (a2 + a3);
    *reinterpret_cast<f32x4*>(partials + (size_t)blockIdx.y * D + col0) = acc;
}

__global__ void k_aggmsg_reduce(const float* __restrict__ partials,
                                float* __restrict__ aggmsg) {
    const int d = blockIdx.x * 256 + threadIdx.x;
    float s = 0.f;
    #pragma unroll
    for (int r = 0; r < 128; ++r) s += partials[(size_t)r * D + d];
    aggmsg[d] = s;
}

// ---------------------------------------------------------------------------
// K4 (layer 0): fused gates, 2 weight rows per wave, staged 16-deep NT
// preload (16 KB in flight/wave). Waves 0..6143: gh (w_hh); 6144..12287:
// gi0 (w_ih). Emits bf16 weight copies (temporal -> LLC) for layers 1-2.
// ---------------------------------------------------------------------------
__global__ __launch_bounds__(256, 4)
void k_gates_f32(const float* __restrict__ w_ih,
                 const float* __restrict__ w_hh,
                 const float* __restrict__ h,
                 const float* __restrict__ aggmsg,
                 const float* __restrict__ b_ih,
                 const float* __restrict__ b_hh,
                 float* __restrict__ gi0,
                 float* __restrict__ gh,
                 unsigned short* __restrict__ wih_bf,
                 unsigned short* __restrict__ whh_bf) {
    const int gwid = (blockIdx.x * blockDim.x + threadIdx.x) >> 6;
    const int lane = threadIdx.x & 63;
    if (gwid < 6144) {
        const int k0 = gwid * 2;
        const float* __restrict__ r0 = w_hh + (size_t)k0 * D;
        const float* __restrict__ r1 = r0 + D;
        float acc[2][8] = {};
        f32x4 w0[8], w1[8];
        #pragma unroll
        for (int i = 0; i < 8; ++i) w0[i] = ldnt4(r0 + i * 256 + lane * 4);
        #pragma unroll
        for (int i = 0; i < 8; ++i) w1[i] = ldnt4(r1 + i * 256 + lane * 4);
        #pragma unroll
        for (int half = 0; half < 2; ++half) {
            #pragma unroll
            for (int i = 0; i < 8; ++i) {
                const int idx = half * 2048 + i * 256 + lane * 4;
                const f32x4 a = w0[i], b = w1[i];
                u16x4 b0, b1;
                b0.x = f2bf(a.x); b0.y = f2bf(a.y); b0.z = f2bf(a.z); b0.w = f2bf(a.w);
                b1.x = f2bf(b.x); b1.y = f2bf(b.y); b1.z = f2bf(b.z); b1.w = f2bf(b.w);
                *reinterpret_cast<u16x4*>(whh_bf + (size_t)k0 * D + idx) = b0;
                *reinterpret_cast<u16x4*>(whh_bf + (size_t)(k0 + 1) * D + idx) = b1;
                if (half == 0) {   // refill this slot for the next half
                    w0[i] = ldnt4(r0 + 2048 + i * 256 + lane * 4);
                    w1[i] = ldnt4(r1 + 2048 + i * 256 + lane * 4);
                }
                #pragma unroll
                for (int j = 0; j < 8; ++j) {
                    const f32x4 hv = ld4(h + j * D + idx);
                    acc[0][j] += a.x * hv.x + a.y * hv.y + a.z * hv.z + a.w * hv.w;
                    acc[1][j] += b.x * hv.x + b.y * hv.y + b.z * hv.z + b.w * hv.w;
                }
            }
        }
        #pragma unroll
        for (int rr = 0; rr < 2; ++rr)
            #pragma unroll
            for (int j = 0; j < 8; ++j) {
                float v = acc[rr][j];
                #pragma unroll
                for (int off = 32; off; off >>= 1) v += __shfl_xor(v, off);
                if (lane == 0) gh[(size_t)j * D3 + k0 + rr] = v + b_hh[k0 + rr];
            }
    } else {
        const int k0 = (gwid - 6144) * 2;
        const float* __restrict__ r0 = w_ih + (size_t)k0 * D;
        const float* __restrict__ r1 = r0 + D;
        float acc[2] = {0.f, 0.f};
        f32x4 w0[8], w1[8];
        #pragma unroll
        for (int i = 0; i < 8; ++i) w0[i] = ldnt4(r0 + i * 256 + lane * 4);
        #pragma unroll
        for (int i = 0; i < 8; ++i) w1[i] = ldnt4(r1 + i * 256 + lane * 4);
        #pragma unroll
        for (int half = 0; half < 2; ++half) {
            #pragma unroll
            for (int i = 0; i < 8; ++i) {
                const int idx = half * 2048 + i * 256 + lane * 4;
                const f32x4 a = w0[i], b = w1[i];
                u16x4 b0, b1;
                b0.x = f2bf(a.x); b0.y = f2bf(a.y); b0.z = f2bf(a.z); b0.w = f2bf(a.w);
                b1.x = f2bf(b.x); b1.y = f2bf(b.y); b1.z = f2bf(b.z); b1.w = f2bf(b.w);
                *reinterpret_cast<u16x4*>(wih_bf + (size_t)k0 * D + idx) = b0;
                *reinterpret_cast<u16x4*>(wih_bf + (size_t)(k0 + 1) * D + idx) = b1;
                if (half == 0) {
                    w0[i] = ldnt4(r0 + 2048 + i * 256 + lane * 4);
                    w1[i] = ldnt4(r1 + 2048 + i * 256 + lane * 4);
                }
                const f32x4 av = ld4(aggmsg + idx);
                acc[0] += a.x * av.x + a.y * av.y + a.z * av.z + a.w * av.w;
                acc[1] += b.x * av.x + b.y * av.y + b.z * av.z + b.w * av.w;
            }
        }
        #pragma unroll
        for (int rr = 0; rr < 2; ++rr) {
            float v = acc[rr];
            #pragma unroll
            for (int off = 32; off; off >>= 1) v += __shfl_xor(v, off);
            if (lane == 0) gi0[k0 + rr] = v + b_ih[k0 + rr];
        }
    }
}

// ---------------------------------------------------------------------------
// K4b (layers 1-2): gates from bf16 copies (LLC-resident). 2 rows/wave,
// 16 uint4 loads all issued up front (8 KB in flight/wave).
// ---------------------------------------------------------------------------
__global__ __launch_bounds__(256, 4)
void k_gates_bf(const unsigned short* __restrict__ wih_bf,
                const unsigned short* __restrict__ whh_bf,
                const float* __restrict__ h,
                const float* __restrict__ aggmsg,
                const float* __restrict__ b_ih,
                const float* __restrict__ b_hh,
                float* __restrict__ gi0,
                float* __restrict__ gh) {
    const int gwid = (blockIdx.x * blockDim.x + threadIdx.x) >> 6;
    const int lane = threadIdx.x & 63;
    if (gwid < 6144) {
        const int k0 = gwid * 2;
        const unsigned short* __restrict__ r0 = whh_bf + (size_t)k0 * D;
        const unsigned short* __restrict__ r1 = r0 + D;
        u32x4 w0[8], w1[8];
        #pragma unroll
        for (int i = 0; i < 8; ++i)
            w0[i] = *reinterpret_cast<const u32x4*>(r0 + i * 512 + lane * 8);
        #pragma unroll
        for (int i = 0; i < 8; ++i)
            w1[i] = *reinterpret_cast<const u32x4*>(r1 + i * 512 + lane * 8);
        float acc[2][8] = {};
        #pragma unroll
        for (int i = 0; i < 8; ++i) {
            const int idx = i * 512 + lane * 8;
            float wa[8], wb[8];
            wa[0] = bf_lo(w0[i].x); wa[1] = bf_hi(w0[i].x);
            wa[2] = bf_lo(w0[i].y); wa[3] = bf_hi(w0[i].y);
            wa[4] = bf_lo(w0[i].z); wa[5] = bf_hi(w0[i].z);
            wa[6] = bf_lo(w0[i].w); wa[7] = bf_hi(w0[i].w);
            wb[0] = bf_lo(w1[i].x); wb[1] = bf_hi(w1[i].x);
            wb[2] = bf_lo(w1[i].y); wb[3] = bf_hi(w1[i].y);
            wb[4] = bf_lo(w1[i].z); wb[5] = bf_hi(w1[i].z);
            wb[6] = bf_lo(w1[i].w); wb[7] = bf_hi(w1[i].w);
            #pragma unroll
            for (int j = 0; j < 8; ++j) {
                const f32x4 h0 = ld4(h + j * D + idx);
                const f32x4 h1 = ld4(h + j * D + idx + 4);
                acc[0][j] += wa[0] * h0.x + wa[1] * h0.y + wa[2] * h0.z + wa[3] * h0.w
                           + wa[4] * h1.x + wa[5] * h1.y + wa[6] * h1.z + wa[7] * h1.w;
                acc[1][j] += wb[0] * h0.x + wb[1] * h0.y + wb[2] * h0.z + wb[3] * h0.w
                           + wb[4] * h1.x + wb[5] * h1.y + wb[6] * h1.z + wb[7] * h1.w;
            }
        }
        #pragma unroll
        for (int rr = 0; rr < 2; ++rr)
            #pragma unroll
            for (int j = 0; j < 8; ++j) {
                float v = acc[rr][j];
                #pragma unroll
                for (int off = 32; off; off >>= 1) v += __shfl_xor(v, off);
                if (lane == 0) gh[(size_t)j * D3 + k0 + rr] = v + b_hh[k0 + rr];
            }
    } else {
        const int k0 = (gwid - 6144) * 2;
        const unsigned short* __restrict__ r0 = wih_bf + (size_t)k0 * D;
        const unsigned short* __restrict__ r1 = r0 + D;
        u32x4 w0[8], w1[8];
        #pragma unroll
        for (int i = 0; i < 8; ++i)
            w0[i] = *reinterpret_cast<const u32x4*>(r0 + i * 512 + lane * 8);
        #pragma unroll
        for (int i = 0; i < 8; ++i)
            w1[i] = *reinterpret_cast<const u32x4*>(r1 + i * 512 + lane * 8);
        float acc[2] = {0.f, 0.f};
        #pragma unroll
        for (int i = 0; i < 8; ++i) {
            const int idx = i * 512 + lane * 8;
            const f32x4 a0 = ld4(aggmsg + idx);
            const f32x4 a1 = ld4(aggmsg + idx + 4);
            acc[0] += bf_lo(w0[i].x) * a0.x + bf_hi(w0[i].x) * a0.y
                    + bf_lo(w0[i].y) * a0.z + bf_hi(w0[i].y) * a0.w
                    + bf_lo(w0[i].z) * a1.x + bf_hi(w0[i].z) * a1.y
                    + bf_lo(w0[i].w) * a1.z + bf_hi(w0[i].w) * a1.w;
            acc[1] += bf_lo(w1[i].x) * a0.x + bf_hi(w1[i].x) * a0.y
                    + bf_lo(w1[i].y) * a0.z + bf_hi(w1[i].y) * a0.w
                    + bf_lo(w1[i].z) * a1.x + bf_hi(w1[i].z) * a1.y
                    + bf_lo(w1[i].w) * a1.z + bf_hi(w1[i].w) * a1.w;
        }
        #pragma unroll
        for (int rr = 0; rr < 2; ++rr) {
            float v = acc[rr];
            #pragma unroll
            for (int off = 32; off; off >>= 1) v += __shfl_xor(v, off);
            if (lane == 0) gi0[k0 + rr] = v + b_ih[k0 + rr];
        }
    }
}

// ---------------------------------------------------------------------------
// K6: GRU pointwise update; rows 0-3 (shared) use gi = b_ih (agg = 0).
// ---------------------------------------------------------------------------
__device__ __forceinline__ float sigmoidf_(float x) {
    return 1.0f / (1.0f + __expf(-x));
}

__global__ void k_gru(const float* __restrict__ gi0,
                      const float* __restrict__ gh,
                      const float* __restrict__ b_ih,
                      float* __restrict__ h,
                      float* __restrict__ svec) {
    const int d = blockIdx.x * 256 + threadIdx.x;
    const float bir = b_ih[d], biz = b_ih[D + d], bin = b_ih[2 * D + d];
    const float gir = gi0[d],  giz = gi0[D + d],  gin = gi0[2 * D + d];
    float ssum = 0.f;
    #pragma unroll
    for (int j = 0; j < 8; ++j) {
        const float ir = (j < 4) ? bir : gir;
        const float iz = (j < 4) ? biz : giz;
        const float in = (j < 4) ? bin : gin;
        const float hr = gh[(size_t)j * D3 + d];
        const float hz = gh[(size_t)j * D3 + D + d];
        const float hn = gh[(size_t)j * D3 + 2 * D + d];
        const float hv = h[j * D + d];
        const float r = sigmoidf_(ir + hr);
        const float z = sigmoidf_(iz + hz);
        const float n = tanhf(in + r * hn);
        const float hnew = (1.f - z) * n + z * hv;
        h[j * D + d] = hnew;
        if (j < 4) ssum += hnew;
    }
    svec[d] = ssum;
}

// ---------------------------------------------------------------------------
// K7: loss = 10 * sum_s mean_d (h0_s - pre_mean_s)^2.
// ---------------------------------------------------------------------------
__global__ void k_loss(const float* __restrict__ h,
                       const float* __restrict__ means,
                       float* __restrict__ out) {
    __shared__ float red[4];
    float acc = 0.f;
    for (int idx = threadIdx.x; idx < 4 * D; idx += 256) {
        const int s = idx >> 12;
        const int d = idx & (D - 1);
        const float diff = h[(4 + s) * D + d] - means[(4 + s) * D + d];
        acc += diff * diff;
    }
    #pragma unroll
    for (int off = 32; off; off >>= 1) acc += __shfl_xor(acc, off);
    const int wave = threadIdx.x >> 6, lane = threadIdx.x & 63;
    if (lane == 0) red[wave] = acc;
    __syncthreads();
    if (threadIdx.x == 0)
        out[0] = (red[0] + red[1] + red[2] + red[3]) * (10.0f / (float)D);
}

// ---------------------------------------------------------------------------
extern "C" void kernel_launch(void* const* d_in, const int* in_sizes, int n_in,
                              void* d_out, int out_size, void* d_ws, size_t ws_size,
                              hipStream_t stream) {
    const float* W    = (const float*)d_in[8];
    const float* w_ih = (const float*)d_in[9];
    const float* w_hh = (const float*)d_in[10];
    const float* b_ih = (const float*)d_in[11];
    const float* b_hh = (const float*)d_in[12];

    float* ws     = (float*)d_ws;
    float* mpart  = ws;                    // 8*16*D
    float* means  = mpart  + 8 * 16 * D;   // 8*D
    float* h      = means  + 8 * D;        // 8*D
    float* svec   = h      + 8 * D;        // D
    float* apart  = svec   + D;            // 128*D
    float* aggmsg = apart  + 128 * D;      // D
    float* gi0    = aggmsg + D;            // D3
    float* gh     = gi0    + D3;           // 8*D3
    float* wbase  = gh     + 8 * D3;
    unsigned short* wih_bf = (unsigned short*)wbase;   // D3*D bf16 = 96 MB
    unsigned short* whh_bf = wih_bf + (size_t)D3 * D;  // D3*D bf16 = 96 MB

    Ptrs8 in8;
    for (int i = 0; i < 8; ++i) in8.p[i] = (const float*)d_in[i];

    k_mean_partial<<<dim3(4, 16, 8), 256, 0, stream>>>(in8, mpart);
    k_mean_finalize<<<16, 256, 0, stream>>>(mpart, means, h, svec);

    for (int l = 0; l < L; ++l) {
        const float* Wl = W + (size_t)l * D * D;
        k_aggmsg_partial<<<dim3(4, 128), 256, 0, stream>>>(Wl, svec, apart);
        k_aggmsg_reduce<<<16, 256, 0, stream>>>(apart, aggmsg);
        if (l == 0)
            k_gates_f32<<<3072, 256, 0, stream>>>(w_ih, w_hh, h, aggmsg,
                                                  b_ih, b_hh, gi0, gh,
                                                  wih_bf, whh_bf);
        else
            k_gates_bf<<<3072, 256, 0, stream>>>(wih_bf, whh_bf, h, aggmsg,
                                                 b_ih, b_hh, gi0, gh);
        k_gru<<<16, 256, 0, stream>>>(gi0, gh, b_ih, h, svec);
    }

    k_loss<<<1, 256, 0, stream>>>(h, means, (float*)d_out);
}

// Round 5
// 397.549 us; speedup vs baseline: 5.5482x; 5.5482x over previous
//
#include <hip/hip_runtime.h>
#include <hip/hip_bf16.h>

// Sizes fixed by the problem
#define B  2048
#define D  4096
#define D3 12288   // 3*D
#define L  3
#define BK 256     // tile width in elements (per weight row per stage)

struct Ptrs8 { const float* p[8]; };

typedef float          f32x4 __attribute__((ext_vector_type(4)));
typedef unsigned int   u32x2 __attribute__((ext_vector_type(2)));
typedef unsigned short u16x4 __attribute__((ext_vector_type(4)));

__device__ __forceinline__ f32x4 ldnt4(const float* p) {
    return __builtin_nontemporal_load(reinterpret_cast<const f32x4*>(p));
}
__device__ __forceinline__ f32x4 ld4(const float* p) {
    return *reinterpret_cast<const f32x4*>(p);
}
// async global->LDS, 16B per lane: LDS dest = base + lane*16 (wave-uniform base)
__device__ __forceinline__ void gload16(const void* g, void* l) {
    __builtin_amdgcn_global_load_lds(
        (const __attribute__((address_space(1))) unsigned int*)g,
        (__attribute__((address_space(3))) unsigned int*)l, 16, 0, 0);
}

__device__ __forceinline__ unsigned short f2bf(float f) {
    union { float f; unsigned int u; } v; v.f = f;
    unsigned int r = v.u + 0x7FFFu + ((v.u >> 16) & 1u);  // round-nearest-even
    return (unsigned short)(r >> 16);
}
__device__ __forceinline__ float bf_lo(unsigned int u) {
    union { unsigned int u; float f; } v; v.u = u << 16; return v.f;
}
__device__ __forceinline__ float bf_hi(unsigned int u) {
    union { unsigned int u; float f; } v; v.u = u & 0xFFFF0000u; return v.f;
}

// ---------------------------------------------------------------------------
// K1: column means of the 8 [B, D] inputs. 2048 blocks (8/CU), 32 rows each,
// 4 independent accumulator streams. NT: inputs streamed once.
// ---------------------------------------------------------------------------
__global__ void k_mean_partial(Ptrs8 in, float* __restrict__ partials) {
    const int cc = blockIdx.x, rc = blockIdx.y, m = blockIdx.z;
    const float* __restrict__ src = in.p[m];
    const int col0 = cc * 1024 + threadIdx.x * 4;
    const size_t base = (size_t)(rc * 32) * D + col0;
    f32x4 a0 = {0,0,0,0}, a1 = {0,0,0,0}, a2 = {0,0,0,0}, a3 = {0,0,0,0};
    #pragma unroll
    for (int r = 0; r < 32; r += 4) {
        a0 += ldnt4(src + base + (size_t)(r + 0) * D);
        a1 += ldnt4(src + base + (size_t)(r + 1) * D);
        a2 += ldnt4(src + base + (size_t)(r + 2) * D);
        a3 += ldnt4(src + base + (size_t)(r + 3) * D);
    }
    const f32x4 acc = (a0 + a1) + (a2 + a3);
    *reinterpret_cast<f32x4*>(partials + ((size_t)(m * 64 + rc)) * D + col0) = acc;
}

__global__ void k_mean_finalize(const float* __restrict__ partials,
                                float* __restrict__ means,
                                float* __restrict__ h,
                                float* __restrict__ svec) {
    const int d = blockIdx.x * 256 + threadIdx.x;
    float mv[8];
    #pragma unroll
    for (int m = 0; m < 8; ++m) {
        float s = 0.f;
        for (int rc = 0; rc < 64; ++rc) s += partials[(size_t)(m * 64 + rc) * D + d];
        mv[m] = s * (1.0f / (float)B);
        means[m * D + d] = mv[m];
    }
    float ssum = 0.f;
    #pragma unroll
    for (int j = 0; j < 4; ++j) {          // shared rows = pre means (inputs 4..7)
        h[j * D + d] = mv[4 + j];
        ssum += mv[4 + j];
    }
    #pragma unroll
    for (int s = 0; s < 4; ++s)            // stream rows = now means (inputs 0..3)
        h[(4 + s) * D + d] = mv[s];
    svec[d] = ssum;
}

// ---------------------------------------------------------------------------
// K3: aggmsg[d'] = sum_d svec[d] * W[d][d'].  1024 blocks (4/CU), 16 rows,
// 4 accumulator streams. NT on W (streamed once per layer).
// ---------------------------------------------------------------------------
__global__ void k_aggmsg_partial(const float* __restrict__ Wl,
                                 const float* __restrict__ svec,
                                 float* __restrict__ partials) {
    const int col0 = blockIdx.x * 1024 + threadIdx.x * 4;
    const int row0 = blockIdx.y * 16;
    f32x4 a0 = {0,0,0,0}, a1 = {0,0,0,0}, a2 = {0,0,0,0}, a3 = {0,0,0,0};
    #pragma unroll
    for (int r = 0; r < 16; r += 4) {
        a0 += svec[row0 + r + 0] * ldnt4(Wl + (size_t)(row0 + r + 0) * D + col0);
        a1 += svec[row0 + r + 1] * ldnt4(Wl + (size_t)(row0 + r + 1) * D + col0);
        a2 += svec[row0 + r + 2] * ldnt4(Wl + (size_t)(row0 + r + 2) * D + col0);
        a3 += svec[row0 + r + 3] * ldnt4(Wl + (size_t)(row0 + r + 3) * D + col0);
    }
    const f32x4 acc = (a0 + a1) + (a2 + a3);
    *reinterpret_cast<f32x4*>(partials + (size_t)blockIdx.y * D + col0) = acc;
}

__global__ void k_aggmsg_reduce(const float* __restrict__ partials,
                                float* __restrict__ aggmsg) {
    const int d = blockIdx.x * 256 + threadIdx.x;
    float s = 0.f;
    for (int r = 0; r < 256; ++r) s += partials[(size_t)r * D + d];
    aggmsg[d] = s;
}

// ---------------------------------------------------------------------------
// K4 (layer 0): fused gates with LDS double-buffered weight staging via
// global_load_lds (depth lives in the LDS-DMA queue, not VGPRs — avoids the
// 64-VGPR spill cliff measured in r2/r4). Blocks 0..767: gh rows (w_hh);
// 768..1535: gi0 rows (w_ih). 16 rows/block (4/wave), 16 tiles of BK=256.
// Emits bf16 weight copies for layers 1-2.
// ---------------------------------------------------------------------------
__global__ __launch_bounds__(256)
void k_gates_f32(const float* __restrict__ w_ih,
                 const float* __restrict__ w_hh,
                 const float* __restrict__ h,
                 const float* __restrict__ aggmsg,
                 const float* __restrict__ b_ih,
                 const float* __restrict__ b_hh,
                 float* __restrict__ gi0,
                 float* __restrict__ gh,
                 unsigned short* __restrict__ wih_bf,
                 unsigned short* __restrict__ whh_bf) {
    __shared__ float sw[2][16][BK];                 // 32 KB
    const bool is_ih = (blockIdx.x >= 768);
    const int  kbase = (is_ih ? blockIdx.x - 768 : blockIdx.x) * 16;
    const float* __restrict__ wsrc = is_ih ? w_ih : w_hh;
    unsigned short* __restrict__ wdst = is_ih ? wih_bf : whh_bf;
    const int wid = threadIdx.x >> 6, lane = threadIdx.x & 63;

    // wave w stages its own rows 4w..4w+3; one call = one row-chunk of 256 f
    auto stage = [&](int t, int b) {
        #pragma unroll
        for (int rr = 0; rr < 4; ++rr) {
            const int row = wid * 4 + rr;
            gload16(wsrc + (size_t)(kbase + row) * D + t * BK + lane * 4,
                    &sw[b][row][0]);
        }
    };

    float acc[4][8] = {};
    stage(0, 0);
    __syncthreads();                                 // drains LDS-DMA (vmcnt)
    for (int t = 0; t < 16; ++t) {
        if (t + 1 < 16) stage(t + 1, (t + 1) & 1);   // prefetch next tile
        const int cb = t & 1;
        f32x4 wreg[4];
        #pragma unroll
        for (int rr = 0; rr < 4; ++rr) {
            const int row = wid * 4 + rr;
            wreg[rr] = *reinterpret_cast<const f32x4*>(&sw[cb][row][lane * 4]);
            u16x4 wb;
            wb.x = f2bf(wreg[rr].x); wb.y = f2bf(wreg[rr].y);
            wb.z = f2bf(wreg[rr].z); wb.w = f2bf(wreg[rr].w);
            *reinterpret_cast<u16x4*>(
                wdst + (size_t)(kbase + row) * D + t * BK + lane * 4) = wb;
        }
        if (!is_ih) {
            #pragma unroll
            for (int j = 0; j < 8; ++j) {
                const f32x4 hv = ld4(h + j * D + t * BK + lane * 4);
                #pragma unroll
                for (int rr = 0; rr < 4; ++rr)
                    acc[rr][j] += wreg[rr].x * hv.x + wreg[rr].y * hv.y
                                + wreg[rr].z * hv.z + wreg[rr].w * hv.w;
            }
        } else {
            const f32x4 av = ld4(aggmsg + t * BK + lane * 4);
            #pragma unroll
            for (int rr = 0; rr < 4; ++rr)
                acc[rr][0] += wreg[rr].x * av.x + wreg[rr].y * av.y
                            + wreg[rr].z * av.z + wreg[rr].w * av.w;
        }
        __syncthreads();                             // buffer flip safety
    }

    if (!is_ih) {
        #pragma unroll
        for (int rr = 0; rr < 4; ++rr)
            #pragma unroll
            for (int j = 0; j < 8; ++j) {
                float v = acc[rr][j];
                #pragma unroll
                for (int off = 32; off; off >>= 1) v += __shfl_xor(v, off);
                if (lane == 0)
                    gh[(size_t)j * D3 + kbase + wid * 4 + rr] = v + b_hh[kbase + wid * 4 + rr];
            }
    } else {
        #pragma unroll
        for (int rr = 0; rr < 4; ++rr) {
            float v = acc[rr][0];
            #pragma unroll
            for (int off = 32; off; off >>= 1) v += __shfl_xor(v, off);
            if (lane == 0)
                gi0[kbase + wid * 4 + rr] = v + b_ih[kbase + wid * 4 + rr];
        }
    }
}

// ---------------------------------------------------------------------------
// K4b (layers 1-2): same pipeline from the bf16 weight copies (LLC-resident).
// Tile = 16 rows x 256 bf16 (512 B/row); one gload16 call stages 2 rows.
// ---------------------------------------------------------------------------
__global__ __launch_bounds__(256)
void k_gates_bf(const unsigned short* __restrict__ wih_bf,
                const unsigned short* __restrict__ whh_bf,
                const float* __restrict__ h,
                const float* __restrict__ aggmsg,
                const float* __restrict__ b_ih,
                const float* __restrict__ b_hh,
                float* __restrict__ gi0,
                float* __restrict__ gh) {
    __shared__ unsigned short sw[2][16][BK];        // 16 KB
    const bool is_ih = (blockIdx.x >= 768);
    const int  kbase = (is_ih ? blockIdx.x - 768 : blockIdx.x) * 16;
    const unsigned short* __restrict__ wsrc = is_ih ? wih_bf : whh_bf;
    const int wid = threadIdx.x >> 6, lane = threadIdx.x & 63;

    // one call stages rows {row, row+1}: lanes 0..31 -> row, 32..63 -> row+1
    auto stage = [&](int t, int b) {
        #pragma unroll
        for (int c = 0; c < 2; ++c) {
            const int row = wid * 4 + c * 2;
            gload16(wsrc + (size_t)(kbase + row + (lane >> 5)) * D
                         + t * BK + (lane & 31) * 8,
                    &sw[b][row][0]);
        }
    };

    float acc[4][8] = {};
    stage(0, 0);
    __syncthreads();
    for (int t = 0; t < 16; ++t) {
        if (t + 1 < 16) stage(t + 1, (t + 1) & 1);
        const int cb = t & 1;
        float wf[4][4];
        #pragma unroll
        for (int rr = 0; rr < 4; ++rr) {
            const u32x2 wu = *reinterpret_cast<const u32x2*>(
                &sw[cb][wid * 4 + rr][lane * 4]);
            wf[rr][0] = bf_lo(wu.x); wf[rr][1] = bf_hi(wu.x);
            wf[rr][2] = bf_lo(wu.y); wf[rr][3] = bf_hi(wu.y);
        }
        if (!is_ih) {
            #pragma unroll
            for (int j = 0; j < 8; ++j) {
                const f32x4 hv = ld4(h + j * D + t * BK + lane * 4);
                #pragma unroll
                for (int rr = 0; rr < 4; ++rr)
                    acc[rr][j] += wf[rr][0] * hv.x + wf[rr][1] * hv.y
                                + wf[rr][2] * hv.z + wf[rr][3] * hv.w;
            }
        } else {
            const f32x4 av = ld4(aggmsg + t * BK + lane * 4);
            #pragma unroll
            for (int rr = 0; rr < 4; ++rr)
                acc[rr][0] += wf[rr][0] * av.x + wf[rr][1] * av.y
                            + wf[rr][2] * av.z + wf[rr][3] * av.w;
        }
        __syncthreads();
    }

    if (!is_ih) {
        #pragma unroll
        for (int rr = 0; rr < 4; ++rr)
            #pragma unroll
            for (int j = 0; j < 8; ++j) {
                float v = acc[rr][j];
                #pragma unroll
                for (int off = 32; off; off >>= 1) v += __shfl_xor(v, off);
                if (lane == 0)
                    gh[(size_t)j * D3 + kbase + wid * 4 + rr] = v + b_hh[kbase + wid * 4 + rr];
            }
    } else {
        #pragma unroll
        for (int rr = 0; rr < 4; ++rr) {
            float v = acc[rr][0];
            #pragma unroll
            for (int off = 32; off; off >>= 1) v += __shfl_xor(v, off);
            if (lane == 0)
                gi0[kbase + wid * 4 + rr] = v + b_ih[kbase + wid * 4 + rr];
        }
    }
}

// ---------------------------------------------------------------------------
// K6: GRU pointwise update; rows 0-3 (shared) use gi = b_ih (agg = 0).
// ---------------------------------------------------------------------------
__device__ __forceinline__ float sigmoidf_(float x) {
    return 1.0f / (1.0f + __expf(-x));
}

__global__ void k_gru(const float* __restrict__ gi0,
                      const float* __restrict__ gh,
                      const float* __restrict__ b_ih,
                      float* __restrict__ h,
                      float* __restrict__ svec) {
    const int d = blockIdx.x * 256 + threadIdx.x;
    const float bir = b_ih[d], biz = b_ih[D + d], bin = b_ih[2 * D + d];
    const float gir = gi0[d],  giz = gi0[D + d],  gin = gi0[2 * D + d];
    float ssum = 0.f;
    #pragma unroll
    for (int j = 0; j < 8; ++j) {
        const float ir = (j < 4) ? bir : gir;
        const float iz = (j < 4) ? biz : giz;
        const float in = (j < 4) ? bin : gin;
        const float hr = gh[(size_t)j * D3 + d];
        const float hz = gh[(size_t)j * D3 + D + d];
        const float hn = gh[(size_t)j * D3 + 2 * D + d];
        const float hv = h[j * D + d];
        const float r = sigmoidf_(ir + hr);
        const float z = sigmoidf_(iz + hz);
        const float n = tanhf(in + r * hn);
        const float hnew = (1.f - z) * n + z * hv;
        h[j * D + d] = hnew;
        if (j < 4) ssum += hnew;
    }
    svec[d] = ssum;
}

// ---------------------------------------------------------------------------
// K7: loss = 10 * sum_s mean_d (h0_s - pre_mean_s)^2.
// ---------------------------------------------------------------------------
__global__ void k_loss(const float* __restrict__ h,
                       const float* __restrict__ means,
                       float* __restrict__ out) {
    __shared__ float red[4];
    float acc = 0.f;
    for (int idx = threadIdx.x; idx < 4 * D; idx += 256) {
        const int s = idx >> 12;
        const int d = idx & (D - 1);
        const float diff = h[(4 + s) * D + d] - means[(4 + s) * D + d];
        acc += diff * diff;
    }
    #pragma unroll
    for (int off = 32; off; off >>= 1) acc += __shfl_xor(acc, off);
    const int wave = threadIdx.x >> 6, lane = threadIdx.x & 63;
    if (lane == 0) red[wave] = acc;
    __syncthreads();
    if (threadIdx.x == 0)
        out[0] = (red[0] + red[1] + red[2] + red[3]) * (10.0f / (float)D);
}

// ---------------------------------------------------------------------------
extern "C" void kernel_launch(void* const* d_in, const int* in_sizes, int n_in,
                              void* d_out, int out_size, void* d_ws, size_t ws_size,
                              hipStream_t stream) {
    const float* W    = (const float*)d_in[8];
    const float* w_ih = (const float*)d_in[9];
    const float* w_hh = (const float*)d_in[10];
    const float* b_ih = (const float*)d_in[11];
    const float* b_hh = (const float*)d_in[12];

    float* ws     = (float*)d_ws;
    float* mpart  = ws;                    // 8*64*D
    float* means  = mpart  + 8 * 64 * D;   // 8*D
    float* h      = means  + 8 * D;        // 8*D
    float* svec   = h      + 8 * D;        // D
    float* apart  = svec   + D;            // 256*D
    float* aggmsg = apart  + 256 * D;      // D
    float* gi0    = aggmsg + D;            // D3
    float* gh     = gi0    + D3;           // 8*D3
    float* wbase  = gh     + 8 * D3;
    unsigned short* wih_bf = (unsigned short*)wbase;   // D3*D bf16 = 96 MB
    unsigned short* whh_bf = wih_bf + (size_t)D3 * D;  // D3*D bf16 = 96 MB

    Ptrs8 in8;
    for (int i = 0; i < 8; ++i) in8.p[i] = (const float*)d_in[i];

    k_mean_partial<<<dim3(4, 64, 8), 256, 0, stream>>>(in8, mpart);
    k_mean_finalize<<<16, 256, 0, stream>>>(mpart, means, h, svec);

    for (int l = 0; l < L; ++l) {
        const float* Wl = W + (size_t)l * D * D;
        k_aggmsg_partial<<<dim3(4, 256), 256, 0, stream>>>(Wl, svec, apart);
        k_aggmsg_reduce<<<16, 256, 0, stream>>>(apart, aggmsg);
        if (l == 0)
            k_gates_f32<<<1536, 256, 0, stream>>>(w_ih, w_hh, h, aggmsg,
                                                  b_ih, b_hh, gi0, gh,
                                                  wih_bf, whh_bf);
        else
            k_gates_bf<<<1536, 256, 0, stream>>>(wih_bf, whh_bf, h, aggmsg,
                                                 b_ih, b_hh, gi0, gh);
        k_gru<<<16, 256, 0, stream>>>(gi0, gh, b_ih, h, svec);
    }

    k_loss<<<1, 256, 0, stream>>>(h, means, (float*)d_out);
}